// Round 1
// 190.208 us; speedup vs baseline: 1.0083x; 1.0083x over previous
//
#include <hip/hip_runtime.h>

#define NS 5      // symbols
#define NW 33     // subcarriers
#define NA 16     // antennas
#define SW 165    // NS*NW
#define MPW 5     // matrices per wave (5*TPM = 55 of 64 lanes active in compute)
#define GM 20     // matrices per block = MPW * (THREADS/64)
#define TPM 11    // threads per matrix
#define CPT 3     // columns per thread
#define THREADS 256

// R10: wave-autonomous restructure. Lessons kept: 256 threads (R9), no tight
// register cap (R5/R7), sFsub as LDS table (R8), A/B fused (R7).
// New: 5 matrices per wave so no matrix crosses a wave boundary -> the
// stage-D->E transpose is wave-internal (in-order per-wave DS + lgkmcnt(0)),
// killing barriers 2 and 3; x staging is per-wave, killing the block-wide
// phase coupling of barrier 1 (only F staging keeps one initial barrier).
__global__ __launch_bounds__(THREADS, 4) void autocorr_kernel(
    const float* __restrict__ x_real, const float* __restrict__ x_imag,
    const float* __restrict__ Fsym_re, const float* __restrict__ Fsym_im,
    const float* __restrict__ Fsub_re, const float* __restrict__ Fsub_im,
    float* __restrict__ out, int NM, int write_complex)
{
    __shared__ float2 sFsym[NS * NS];   // [s][t]
    __shared__ float2 sFsub[NW * NW];   // [w][v] row-major (symmetric matrix)
    __shared__ float2 buf[GM][SW];      // x col-major [w][t] -> T2 col-major [v][p<3]

    const int tid = threadIdx.x;

    // ---- stage F matrices into LDS (cooperative; the ONLY barrier) ----
    for (int i = tid; i < NW * NW; i += THREADS)
        sFsub[i] = make_float2(Fsub_re[i], Fsub_im[i]);
    if (tid < NS * NS) sFsym[tid] = make_float2(Fsym_re[tid], Fsym_im[tid]);
    __syncthreads();

    const int wave = tid >> 6;
    const int lane = tid & 63;
    const int Mw = blockIdx.x * GM + wave * MPW;       // this wave's first matrix
    float2* const wbuf = &buf[wave * MPW][0];          // wave-private 5*SW region

    // ---- per-wave x staging, col-major per matrix: wbuf[g*SW + w*NS + t] ----
    for (int e = lane; e < MPW * SW; e += 64) {
        const int g = e / SW, r = e - g * SW;
        const int t = r / NW, w = r - t * NW;
        const int M = Mw + g;
        float2 val = make_float2(0.f, 0.f);
        if (M < NM) {
            const int n = M >> 4, a = M & 15;
            const int off = ((n * NS + t) * NA + a) * NW + w;
            val = make_float2(x_real[off], x_imag[off]);
        }
        wbuf[g * SW + w * NS + t] = val;
    }
    // Wave-synchronous LDS: DS ops from one wave complete in order. Wait for
    // our ds_writes, and the memory clobber stops the compiler hoisting the
    // dependent ds_reads above this point. No __syncthreads needed.
    asm volatile("s_waitcnt lgkmcnt(0)" ::: "memory");

    const int g = lane / TPM;                 // 0..4 active, 5 for idle lanes
    const int j = lane - g * TPM;
    const bool act = (lane < MPW * TPM);      // 55 of 64 lanes compute
    const int gg = act ? g : 0;               // clamp for pointer formation
    const int M = Mw + g;
    const int c0 = 3 * j;

    // ---- Fused A+B: V[t][k] = sum_w x[t][w] * Fsub[w][c0+k] ----
    float2 V[NS][CPT];
#pragma unroll
    for (int t = 0; t < NS; ++t)
#pragma unroll
        for (int k = 0; k < CPT; ++k) V[t][k] = make_float2(0.f, 0.f);
    if (act) {
        const float2* bp = wbuf + gg * SW;
#pragma unroll 3
        for (int w = 0; w < NW; ++w) {
            float2 xc[NS];
#pragma unroll
            for (int t = 0; t < NS; ++t) xc[t] = bp[w * NS + t];   // 5 consecutive float2
            float2 fv[CPT];
#pragma unroll
            for (int k = 0; k < CPT; ++k) fv[k] = sFsub[w * NW + c0 + k];
#pragma unroll
            for (int t = 0; t < NS; ++t)
#pragma unroll
                for (int k = 0; k < CPT; ++k) {
                    V[t][k].x = fmaf(xc[t].x, fv[k].x, V[t][k].x);
                    V[t][k].x = fmaf(-xc[t].y, fv[k].y, V[t][k].x);
                    V[t][k].y = fmaf(xc[t].x, fv[k].y, V[t][k].y);
                    V[t][k].y = fmaf(xc[t].y, fv[k].x, V[t][k].y);
                }
        }
    }

    // ---- X = F_sym*V (thread-local); P = |X|^2; Stage D (Hermitian p<3) -> T2 ----
    float2 T2[3][CPT];
#pragma unroll
    for (int p = 0; p < 3; ++p)
#pragma unroll
        for (int k = 0; k < CPT; ++k) T2[p][k] = make_float2(0.f, 0.f);
    if (act) {
#pragma unroll
        for (int s = 0; s < NS; ++s) {
            float2 X[CPT];
#pragma unroll
            for (int k = 0; k < CPT; ++k) X[k] = make_float2(0.f, 0.f);
#pragma unroll
            for (int t = 0; t < NS; ++t) {
                float2 f = sFsym[s * NS + t];   // broadcast
#pragma unroll
                for (int k = 0; k < CPT; ++k) {
                    X[k].x = fmaf(f.x, V[t][k].x, X[k].x);
                    X[k].x = fmaf(-f.y, V[t][k].y, X[k].x);
                    X[k].y = fmaf(f.x, V[t][k].y, X[k].y);
                    X[k].y = fmaf(f.y, V[t][k].x, X[k].y);
                }
            }
            float P[CPT];
#pragma unroll
            for (int k = 0; k < CPT; ++k)
                P[k] = X[k].x * X[k].x + X[k].y * X[k].y;
#pragma unroll
            for (int p = 0; p < 3; ++p) {
                float2 f = sFsym[s * NS + p];   // conj in MAC
#pragma unroll
                for (int k = 0; k < CPT; ++k) {
                    T2[p][k].x = fmaf(f.x, P[k], T2[p][k].x);
                    T2[p][k].y = fmaf(-f.y, P[k], T2[p][k].y);
                }
            }
        }
        // T2 col-major transpose through wave-private LDS: wbuf[g*SW + v*3 + p].
        // Safe WAR vs the x reads above: single instruction stream per wave, the
        // ds_reads issue before these ds_writes for every lane, and DS executes
        // per-wave in order; register dataflow (V feeds T2) pins compiler order.
#pragma unroll
        for (int k = 0; k < CPT; ++k)
#pragma unroll
            for (int p = 0; p < 3; ++p)
                wbuf[gg * SW + (c0 + k) * 3 + p] = T2[p][k];
    }
    // Wave-sync: T2 visible to all lanes of this wave before stage E reads it.
    asm volatile("s_waitcnt lgkmcnt(0)" ::: "memory");

    // ---- Stage E: Y[p][q] = sum_v T2[p][v]*conj(Fsub[q][v]), q = c0+k ----
    if (act) {
        const float2* bp = wbuf + gg * SW;
        if (!write_complex) {
            // Real part only (harness output is float32 = Re(Y)).
            float Yr[3][CPT];
#pragma unroll
            for (int p = 0; p < 3; ++p)
#pragma unroll
                for (int k = 0; k < CPT; ++k) Yr[p][k] = 0.f;
#pragma unroll 3
            for (int v = 0; v < NW; ++v) {
                float2 tc[3];
#pragma unroll
                for (int p = 0; p < 3; ++p) tc[p] = bp[v * 3 + p];   // broadcast within matrix
                float2 fw[CPT];
#pragma unroll
                for (int k = 0; k < CPT; ++k) fw[k] = sFsub[(c0 + k) * NW + v]; // = Fsub[q][v]
#pragma unroll
                for (int p = 0; p < 3; ++p)
#pragma unroll
                    for (int k = 0; k < CPT; ++k) {
                        // Re(tc * conj(fw)) = tc.x*fw.x + tc.y*fw.y
                        Yr[p][k] = fmaf(tc[p].x, fw[k].x, Yr[p][k]);
                        Yr[p][k] = fmaf(tc[p].y, fw[k].y, Yr[p][k]);
                    }
            }
            if (M < NM) {
                int n = M >> 4, a = M & 15;
                int obase = ((n * NS) * NA + a) * NW;
#pragma unroll
                for (int p = 0; p < 3; ++p) {
                    const int pp = (NS - p) % NS;   // 0,4,3
#pragma unroll
                    for (int k = 0; k < CPT; ++k) {
                        const int q = c0 + k;
                        const int qq = (NW - q) % NW;
                        out[obase + p * (NA * NW) + q] = Yr[p][k];
                        out[obase + pp * (NA * NW) + qq] = Yr[p][k];
                    }
                }
            }
        } else {
            // Fallback: full complex output (not expected on this harness).
            float2 Y[3][CPT];
#pragma unroll
            for (int p = 0; p < 3; ++p)
#pragma unroll
                for (int k = 0; k < CPT; ++k) Y[p][k] = make_float2(0.f, 0.f);
            for (int v = 0; v < NW; ++v) {
                float2 tc[3];
#pragma unroll
                for (int p = 0; p < 3; ++p) tc[p] = bp[v * 3 + p];
                float2 fw[CPT];
#pragma unroll
                for (int k = 0; k < CPT; ++k) fw[k] = sFsub[(c0 + k) * NW + v];
#pragma unroll
                for (int p = 0; p < 3; ++p)
#pragma unroll
                    for (int k = 0; k < CPT; ++k) {
                        Y[p][k].x = fmaf(tc[p].x, fw[k].x, Y[p][k].x);
                        Y[p][k].x = fmaf(tc[p].y, fw[k].y, Y[p][k].x);
                        Y[p][k].y = fmaf(tc[p].y, fw[k].x, Y[p][k].y);
                        Y[p][k].y = fmaf(-tc[p].x, fw[k].y, Y[p][k].y);
                    }
            }
            if (M < NM) {
                int n = M >> 4, a = M & 15;
#pragma unroll
                for (int p = 0; p < 3; ++p) {
                    const int pp = (NS - p) % NS;
#pragma unroll
                    for (int k = 0; k < CPT; ++k) {
                        const int q = c0 + k;
                        const int qq = (NW - q) % NW;
                        ((float2*)out)[((n * NS + p) * NA + a) * NW + q] = Y[p][k];
                        ((float2*)out)[((n * NS + pp) * NA + a) * NW + qq] =
                            make_float2(Y[p][k].x, -Y[p][k].y);
                    }
                }
            }
        }
    }
}

extern "C" void kernel_launch(void* const* d_in, const int* in_sizes, int n_in,
                              void* d_out, int out_size, void* d_ws, size_t ws_size,
                              hipStream_t stream) {
    const float* x_real  = (const float*)d_in[0];
    const float* x_imag  = (const float*)d_in[1];
    const float* Fsym_re = (const float*)d_in[2];
    const float* Fsym_im = (const float*)d_in[3];
    const float* Fsub_re = (const float*)d_in[4];
    const float* Fsub_im = (const float*)d_in[5];

    const int NM = in_sizes[0] / SW;
    const long long n_cplx = (long long)in_sizes[0];
    const int write_complex = ((long long)out_size >= 2 * n_cplx) ? 1 : 0;

    const int blocks = (NM + GM - 1) / GM;

    autocorr_kernel<<<blocks, THREADS, 0, stream>>>(
        x_real, x_imag, Fsym_re, Fsym_im, Fsub_re, Fsub_im,
        (float*)d_out, NM, write_complex);
}

// Round 2
// 187.781 us; speedup vs baseline: 1.0213x; 1.0129x over previous
//
#include <hip/hip_runtime.h>

#define NS 5      // symbols
#define NW 33     // subcarriers
#define NA 16     // antennas
#define SW 165    // NS*NW
#define MPW 5     // matrices per wave (5*TPM = 55 of 64 lanes active in compute)
#define GM 20     // matrices per block = MPW * (THREADS/64)
#define TPM 11    // threads per matrix
#define CPT 3     // columns per thread
#define THREADS 256

// R11: packed complex math via v_pk_fma_f32 (VOP3P). A complex MAC is 2 packed
// FMAs (op_sel does the broadcast/swap/negate in-instruction) instead of 4
// scalar v_fma_f32 -> ~2x fewer VALU issue slots on the dominant instruction
// class. Structure identical to R10 (wave-autonomous, 1 barrier, GM=20).
typedef float f2 __attribute__((ext_vector_type(2)));

// z += x * f (complex).  z=(zr,zi) x=(xr,xi) f=(fr,fi)
//   inst1: (zr,zi) += (xr,xi)*(fr,fr)        [s1 broadcast lo]
//   inst2: (zr,zi) += (-xi,xr)*(fi,fi)       [s0 swapped, neg lo; s1 broadcast hi]
__device__ __forceinline__ void cmac(f2& z, f2 x, f2 f) {
    asm("v_pk_fma_f32 %0, %1, %2, %0 op_sel:[0,0,0] op_sel_hi:[1,0,1]"
        : "+v"(z) : "v"(x), "v"(f));
    asm("v_pk_fma_f32 %0, %1, %2, %0 op_sel:[1,1,0] op_sel_hi:[0,1,1] neg_lo:[1,0,0]"
        : "+v"(z) : "v"(x), "v"(f));
}

// z += conj(f) * P, P real broadcast pair Pp=(P,P):
//   lo: zr += f.x*P ; hi: zi += -(f.y)*P
__device__ __forceinline__ void cmacr(f2& z, f2 f, f2 Pp) {
    asm("v_pk_fma_f32 %0, %1, %2, %0 op_sel:[0,0,0] op_sel_hi:[1,1,1] neg_hi:[1,0,0]"
        : "+v"(z) : "v"(f), "v"(Pp));
}

// plain packed: z += a*b elementwise (lo*lo, hi*hi)
__device__ __forceinline__ void pkfma(f2& z, f2 a, f2 b) {
    asm("v_pk_fma_f32 %0, %1, %2, %0 op_sel:[0,0,0] op_sel_hi:[1,1,1]"
        : "+v"(z) : "v"(a), "v"(b));
}

__global__ __launch_bounds__(THREADS, 4) void autocorr_kernel(
    const float* __restrict__ x_real, const float* __restrict__ x_imag,
    const float* __restrict__ Fsym_re, const float* __restrict__ Fsym_im,
    const float* __restrict__ Fsub_re, const float* __restrict__ Fsub_im,
    float* __restrict__ out, int NM, int write_complex)
{
    __shared__ f2 sFsym[NS * NS];   // [s][t]
    __shared__ f2 sFsub[NW * NW];   // [w][v] row-major (symmetric matrix)
    __shared__ f2 buf[GM][SW];      // x col-major [w][t] -> T2 col-major [v][p<3]

    const int tid = threadIdx.x;

    // ---- stage F matrices into LDS (cooperative; the ONLY barrier) ----
    for (int i = tid; i < NW * NW; i += THREADS)
        sFsub[i] = (f2){Fsub_re[i], Fsub_im[i]};
    if (tid < NS * NS) sFsym[tid] = (f2){Fsym_re[tid], Fsym_im[tid]};
    __syncthreads();

    const int wave = tid >> 6;
    const int lane = tid & 63;
    const int Mw = blockIdx.x * GM + wave * MPW;       // this wave's first matrix
    f2* const wbuf = &buf[wave * MPW][0];              // wave-private 5*SW region

    // ---- per-wave x staging, col-major per matrix: wbuf[g*SW + w*NS + t] ----
    for (int e = lane; e < MPW * SW; e += 64) {
        const int g = e / SW, r = e - g * SW;
        const int t = r / NW, w = r - t * NW;
        const int M = Mw + g;
        f2 val = (f2){0.f, 0.f};
        if (M < NM) {
            const int n = M >> 4, a = M & 15;
            const int off = ((n * NS + t) * NA + a) * NW + w;
            val = (f2){x_real[off], x_imag[off]};
        }
        wbuf[g * SW + w * NS + t] = val;
    }
    // Wave-synchronous LDS: per-wave DS ops complete in order; wait for our
    // ds_writes; memory clobber keeps dependent ds_reads below this point.
    asm volatile("s_waitcnt lgkmcnt(0)" ::: "memory");

    const int g = lane / TPM;                 // 0..4 active, 5 for idle lanes
    const int j = lane - g * TPM;
    const bool act = (lane < MPW * TPM);      // 55 of 64 lanes compute
    const int gg = act ? g : 0;               // clamp for pointer formation
    const int M = Mw + g;
    const int c0 = 3 * j;

    // ---- Fused A+B: V[t][k] = sum_w x[t][w] * Fsub[w][c0+k] ----
    f2 V[NS][CPT];
#pragma unroll
    for (int t = 0; t < NS; ++t)
#pragma unroll
        for (int k = 0; k < CPT; ++k) V[t][k] = (f2){0.f, 0.f};
    if (act) {
        const f2* bp = wbuf + gg * SW;
#pragma unroll 3
        for (int w = 0; w < NW; ++w) {
            f2 xc[NS];
#pragma unroll
            for (int t = 0; t < NS; ++t) xc[t] = bp[w * NS + t];   // 5 consecutive f2
            f2 fv[CPT];
#pragma unroll
            for (int k = 0; k < CPT; ++k) fv[k] = sFsub[w * NW + c0 + k];
#pragma unroll
            for (int t = 0; t < NS; ++t)
#pragma unroll
                for (int k = 0; k < CPT; ++k)
                    cmac(V[t][k], xc[t], fv[k]);   // 2 pk_fma, was 4 fma
        }
    }

    // ---- X = F_sym*V (thread-local); P = |X|^2; Stage D (Hermitian p<3) -> T2 ----
    f2 T2[3][CPT];
#pragma unroll
    for (int p = 0; p < 3; ++p)
#pragma unroll
        for (int k = 0; k < CPT; ++k) T2[p][k] = (f2){0.f, 0.f};
    if (act) {
#pragma unroll
        for (int s = 0; s < NS; ++s) {
            f2 X[CPT];
#pragma unroll
            for (int k = 0; k < CPT; ++k) X[k] = (f2){0.f, 0.f};
#pragma unroll
            for (int t = 0; t < NS; ++t) {
                f2 f = sFsym[s * NS + t];   // broadcast
#pragma unroll
                for (int k = 0; k < CPT; ++k)
                    cmac(X[k], f, V[t][k]);   // X += f*V, 2 pk_fma
            }
#pragma unroll
            for (int k = 0; k < CPT; ++k) {
                const float Pv = X[k].x * X[k].x + X[k].y * X[k].y;
                const f2 Pp = (f2){Pv, Pv};
#pragma unroll
                for (int p = 0; p < 3; ++p)
                    cmacr(T2[p][k], sFsym[s * NS + p], Pp);  // T2 += conj(f)*P, 1 pk_fma
            }
        }
        // T2 col-major transpose through wave-private LDS: wbuf[g*SW + v*3 + p].
        // WAR-safe vs x reads: single per-wave instruction stream, in-order DS.
#pragma unroll
        for (int k = 0; k < CPT; ++k)
#pragma unroll
            for (int p = 0; p < 3; ++p)
                wbuf[gg * SW + (c0 + k) * 3 + p] = T2[p][k];
    }
    // Wave-sync: T2 visible to all lanes of this wave before stage E reads it.
    asm volatile("s_waitcnt lgkmcnt(0)" ::: "memory");

    // ---- Stage E: Y[p][q] = sum_v T2[p][v]*conj(Fsub[q][v]), q = c0+k ----
    if (act) {
        const f2* bp = wbuf + gg * SW;
        if (!write_complex) {
            // Real part only: Re(tc*conj(fw)) = tc.x*fw.x + tc.y*fw.y.
            // Accumulate the two products in packed halves, fold at the end.
            f2 Ypk[3][CPT];
#pragma unroll
            for (int p = 0; p < 3; ++p)
#pragma unroll
                for (int k = 0; k < CPT; ++k) Ypk[p][k] = (f2){0.f, 0.f};
#pragma unroll 3
            for (int v = 0; v < NW; ++v) {
                f2 tc[3];
#pragma unroll
                for (int p = 0; p < 3; ++p) tc[p] = bp[v * 3 + p];   // broadcast within matrix
                f2 fw[CPT];
#pragma unroll
                for (int k = 0; k < CPT; ++k) fw[k] = sFsub[(c0 + k) * NW + v]; // = Fsub[q][v]
#pragma unroll
                for (int p = 0; p < 3; ++p)
#pragma unroll
                    for (int k = 0; k < CPT; ++k)
                        pkfma(Ypk[p][k], tc[p], fw[k]);   // 1 pk_fma, was 2 fma
            }
            if (M < NM) {
                int n = M >> 4, a = M & 15;
                int obase = ((n * NS) * NA + a) * NW;
#pragma unroll
                for (int p = 0; p < 3; ++p) {
                    const int pp = (NS - p) % NS;   // 0,4,3
#pragma unroll
                    for (int k = 0; k < CPT; ++k) {
                        const int q = c0 + k;
                        const int qq = (NW - q) % NW;
                        const float Yr = Ypk[p][k].x + Ypk[p][k].y;
                        out[obase + p * (NA * NW) + q] = Yr;
                        out[obase + pp * (NA * NW) + qq] = Yr;
                    }
                }
            }
        } else {
            // Fallback: full complex output (not expected on this harness).
            f2 Y[3][CPT];
#pragma unroll
            for (int p = 0; p < 3; ++p)
#pragma unroll
                for (int k = 0; k < CPT; ++k) Y[p][k] = (f2){0.f, 0.f};
            for (int v = 0; v < NW; ++v) {
                f2 tc[3];
#pragma unroll
                for (int p = 0; p < 3; ++p) tc[p] = bp[v * 3 + p];
                f2 fw[CPT];
#pragma unroll
                for (int k = 0; k < CPT; ++k) fw[k] = sFsub[(c0 + k) * NW + v];
#pragma unroll
                for (int p = 0; p < 3; ++p)
#pragma unroll
                    for (int k = 0; k < CPT; ++k) {
                        Y[p][k].x = fmaf(tc[p].x, fw[k].x, Y[p][k].x);
                        Y[p][k].x = fmaf(tc[p].y, fw[k].y, Y[p][k].x);
                        Y[p][k].y = fmaf(tc[p].y, fw[k].x, Y[p][k].y);
                        Y[p][k].y = fmaf(-tc[p].x, fw[k].y, Y[p][k].y);
                    }
            }
            if (M < NM) {
                int n = M >> 4, a = M & 15;
#pragma unroll
                for (int p = 0; p < 3; ++p) {
                    const int pp = (NS - p) % NS;
#pragma unroll
                    for (int k = 0; k < CPT; ++k) {
                        const int q = c0 + k;
                        const int qq = (NW - q) % NW;
                        ((float2*)out)[((n * NS + p) * NA + a) * NW + q] =
                            make_float2(Y[p][k].x, Y[p][k].y);
                        ((float2*)out)[((n * NS + pp) * NA + a) * NW + qq] =
                            make_float2(Y[p][k].x, -Y[p][k].y);
                    }
                }
            }
        }
    }
}

extern "C" void kernel_launch(void* const* d_in, const int* in_sizes, int n_in,
                              void* d_out, int out_size, void* d_ws, size_t ws_size,
                              hipStream_t stream) {
    const float* x_real  = (const float*)d_in[0];
    const float* x_imag  = (const float*)d_in[1];
    const float* Fsym_re = (const float*)d_in[2];
    const float* Fsym_im = (const float*)d_in[3];
    const float* Fsub_re = (const float*)d_in[4];
    const float* Fsub_im = (const float*)d_in[5];

    const int NM = in_sizes[0] / SW;
    const long long n_cplx = (long long)in_sizes[0];
    const int write_complex = ((long long)out_size >= 2 * n_cplx) ? 1 : 0;

    const int blocks = (NM + GM - 1) / GM;

    autocorr_kernel<<<blocks, THREADS, 0, stream>>>(
        x_real, x_imag, Fsym_re, Fsym_im, Fsub_re, Fsub_im,
        (float*)d_out, NM, write_complex);
}